// Round 1
// baseline (655.996 us; speedup 1.0000x reference)
//
#include <hip/hip_runtime.h>
#include <cstddef>

#define BB 2048
#define TT 200
#define HH 256
#define KK 8
#define XP 260   // LDS pitch for gathered rows (float4-aligned, breaks 16-way conflicts)

// workspace layout (in floats)
#define WS_M2T 0
#define WS_D   65536
#define WS_E   65792
#define WS_F   66048
#define WS_IDX 66112   // 16384 ints
#define WS_W   82496   // 16384 floats

// ---------------------------------------------------------------------------
// Kernel A: M2T[l][i] = sum_j Wk[i,j]*Wq[l,j]  (i.e. (Wk Wq^T)^T, stored so the
// per-b qk pass reads it coalesced), d = Wk@bq, e = Wq@bk, f = bk.bq
// ---------------------------------------------------------------------------
__global__ __launch_bounds__(256) void prep_kernel(
    const float* __restrict__ Wq, const float* __restrict__ bq,
    const float* __restrict__ Wk, const float* __restrict__ bk,
    float* __restrict__ M2T, float* __restrict__ dvec,
    float* __restrict__ evec, float* __restrict__ fsc) {
  const int l = blockIdx.x, i = threadIdx.x;
  __shared__ float s_wq[HH], s_bq[HH], s_bk[HH], s_red[HH];
  s_wq[i] = Wq[(size_t)l * HH + i];
  s_bq[i] = bq[i];
  s_bk[i] = bk[i];
  __syncthreads();
  const float* wk = Wk + (size_t)i * HH;
  float acc = 0.f, dd = 0.f;
#pragma unroll 8
  for (int j = 0; j < HH; ++j) {
    float wkj = wk[j];
    acc += s_wq[j] * wkj;
    dd  += s_bq[j] * wkj;
  }
  M2T[(size_t)l * HH + i] = acc;   // coalesced store
  if (l == 0) dvec[i] = dd;
  s_red[i] = s_wq[i] * s_bk[i];
  __syncthreads();
  for (int s = 128; s > 0; s >>= 1) {
    if (i < s) s_red[i] += s_red[i + s];
    __syncthreads();
  }
  if (i == 0) {
    evec[l] = s_red[0];
    if (l == 0) {
      float ff = 0.f;
      for (int j = 0; j < HH; ++j) ff += s_bq[j] * s_bk[j];
      *fsc = ff;
    }
  }
}

// ---------------------------------------------------------------------------
// Kernel B: one block per batch row. qk = M2T.cs + d, scores = x.qk + qb,
// masked softmax, exact top-8 (jax.lax.top_k tie-break), writes attn row,
// selected (as float), and (gather idx, weight) to workspace.
// ---------------------------------------------------------------------------
__global__ __launch_bounds__(256) void attn_kernel(
    const float* __restrict__ CS, const float* __restrict__ X,
    const int* __restrict__ VM,
    const float* __restrict__ M2T, const float* __restrict__ dvec,
    const float* __restrict__ evec, const float* __restrict__ fsc,
    float* __restrict__ out, int* __restrict__ wsIdx, float* __restrict__ wsW) {
  const int tid = threadIdx.x, b = blockIdx.x;
  __shared__ float s_qk[HH], s_sc[TT], s_cand[TT], s_red[HH];
  __shared__ int   s_hist[TT];
  __shared__ int   s_cnt;
  __shared__ float s_qb, s_dS;
  __shared__ int   s_selI[KK];
  __shared__ float s_selV[KK];

  // ---- visit mask + count ----
  int m = 0;
  if (tid < TT) m = (VM[(size_t)b * TT + tid] != 0) ? 1 : 0;
  if (tid == 0) s_cnt = 0;
  __syncthreads();
  unsigned long long bal = __ballot(m);
  if ((tid & 63) == 0) atomicAdd(&s_cnt, (int)__popcll(bal));

  // ---- qk[i] = d[i] + sum_l cs[l]*M2T[l][i]  (cs[l] wave-uniform -> s_load) ----
  const float* csr = CS + (size_t)b * HH;
  float acc = dvec[tid];
#pragma unroll 4
  for (int l = 0; l < HH; ++l) acc += csr[l] * M2T[(size_t)l * HH + tid];
  s_qk[tid] = acc * 0.0625f;            // pre-scale by 1/sqrt(256)
  s_red[tid] = evec[tid] * csr[tid];    // qb partial
  __syncthreads();
  const int cnt = s_cnt;
  if (tid < TT) s_hist[tid] = (m && (tid < cnt - 1)) ? 1 : 0;
  for (int s = 128; s > 0; s >>= 1) {
    if (tid < s) s_red[tid] += s_red[tid + s];
    __syncthreads();
  }
  if (tid == 0) s_qb = (s_red[0] + fsc[0]) * 0.0625f;
  __syncthreads();

  // ---- scores: wave w handles 50 t's; lane j owns float4 at h=4j ----
  {
    const int w = tid >> 6, lane = tid & 63;
    const float* xrow = X + (size_t)b * TT * HH;
    const float4 q4 = ((const float4*)s_qk)[lane];
    const float qb = s_qb;
#pragma unroll 2
    for (int t = w * 50; t < w * 50 + 50; ++t) {
      float4 xv = *(const float4*)(xrow + (size_t)t * HH + lane * 4);
      float p = xv.x * q4.x + xv.y * q4.y + xv.z * q4.z + xv.w * q4.w;
#pragma unroll
      for (int off = 32; off; off >>= 1) p += __shfl_xor(p, off);
      if (lane == 0) s_sc[t] = p + qb;
    }
  }
  __syncthreads();

  // ---- masked softmax ----
  float v = (tid < TT && s_hist[tid]) ? s_sc[tid] : -3.4e38f;
  s_red[tid] = v;
  __syncthreads();
  for (int s = 128; s > 0; s >>= 1) {
    if (tid < s) s_red[tid] = fmaxf(s_red[tid], s_red[tid + s]);
    __syncthreads();
  }
  const float mx = s_red[0];
  __syncthreads();
  float p = (tid < TT && s_hist[tid]) ? expf(s_sc[tid] - mx) : 0.f;
  s_red[tid] = p;
  __syncthreads();
  for (int s = 128; s > 0; s >>= 1) {
    if (tid < s) s_red[tid] += s_red[tid + s];
    __syncthreads();
  }
  const float denom = s_red[0];
  __syncthreads();
  if (tid < TT) s_cand[tid] = s_hist[tid] ? (p / denom) : -1.0f;
  __syncthreads();

  // ---- top-8, wave 0 only: 8 rounds of (value desc, index asc) argmax ----
  if (tid < 64) {
    float lv[4]; int lt[4];
#pragma unroll
    for (int q = 0; q < 4; ++q) {
      int t = tid + 64 * q;
      lv[q] = (t < TT) ? s_cand[t] : -2.0f;
      lt[q] = t;
    }
    for (int r = 0; r < KK; ++r) {
      float bv = -2.5f; int bi = 1 << 30;
#pragma unroll
      for (int q = 0; q < 4; ++q)
        if (lv[q] > bv) { bv = lv[q]; bi = lt[q]; }  // ascending t: > keeps min idx
#pragma unroll
      for (int off = 32; off; off >>= 1) {
        float ov = __shfl_xor(bv, off);
        int   oi = __shfl_xor(bi, off);
        if (ov > bv || (ov == bv && oi < bi)) { bv = ov; bi = oi; }
      }
      if (tid == 0) { s_selI[r] = bi; s_selV[r] = bv; }
#pragma unroll
      for (int q = 0; q < 4; ++q)
        if (lt[q] == bi) lv[q] = -3.0f;   // remove winner
    }
    if (tid == 0) {
      float S = 0.f;
      for (int r = 0; r < KK; ++r) S += fmaxf(s_selV[r], 0.f);
      s_dS = fmaxf(S, 1.1920929e-07f);    // np.finfo(float32).eps
    }
  }
  __syncthreads();

  // ---- outputs ----
  float* out_attn = out + (size_t)BB * HH + (size_t)b * TT;
  if (tid < TT) out_attn[tid] = 0.f;
  __syncthreads();
  if (tid < KK) {
    float vvv = s_selV[tid];
    int   bi  = s_selI[tid];
    float wf  = fmaxf(vvv, 0.f) / s_dS;
    int ok = (vvv >= 0.f);          // history slot (matches sel_mask semantics)
    if (ok) out_attn[bi] = wf;
    out[(size_t)BB * HH + (size_t)BB * TT + (size_t)b * KK + tid] =
        ok ? (float)bi : -1.0f;
    wsIdx[b * KK + tid] = ok ? bi : 0;   // gather t=0 for dead slots (weight 0)
    wsW[b * KK + tid] = wf;
  }
}

// ---------------------------------------------------------------------------
// Kernel C: summary. 256 blocks x 8 b's = 64 gathered rows/block.
// Register-tiled fp32 GEMM (8 rows x 8 cols per thread) vs Wv, fused
// relu + per-b weighted reduction in the epilogue.
// Thread (ty=tid/32, tx=tid&31): rows 8ty..8ty+7 == all 8 slots of b=bb*8+ty.
// ---------------------------------------------------------------------------
__global__ __launch_bounds__(256) void summ_kernel(
    const float* __restrict__ X, const float* __restrict__ Wv,
    const float* __restrict__ bvv,
    const int* __restrict__ wsIdx, const float* __restrict__ wsW,
    float* __restrict__ out) {
  const int tid = threadIdx.x, bb = blockIdx.x;
  __shared__ float xs[64 * XP];
  __shared__ int   s_gi[64];
  __shared__ float s_w[64];
  if (tid < 64) {
    s_gi[tid] = wsIdx[bb * 64 + tid];
    s_w[tid]  = wsW[bb * 64 + tid];
  }
  __syncthreads();
  // gather 64 rows x 256 floats (float4, coalesced per row)
#pragma unroll
  for (int it = 0; it < 16; ++it) {
    int fidx = it * 256 + tid;
    int row = fidx >> 6, c = fidx & 63;
    int bloc = bb * 8 + (row >> 3);
    int t = s_gi[row];
    float4 xv = *(const float4*)(X + ((size_t)bloc * TT + t) * HH + c * 4);
    *(float4*)(xs + row * XP + c * 4) = xv;
  }
  __syncthreads();

  const int ty = tid >> 5, tx = tid & 31;
  float accr[8][8];
#pragma unroll
  for (int r = 0; r < 8; ++r)
#pragma unroll
    for (int c = 0; c < 8; ++c) accr[r][c] = 0.f;

  const float* wvp = Wv + tx * 8;
  for (int ig = 0; ig < 64; ++ig) {
    float4 a4[8];
#pragma unroll
    for (int r = 0; r < 8; ++r)
      a4[r] = *(const float4*)(xs + (ty * 8 + r) * XP + ig * 4);
#pragma unroll
    for (int k = 0; k < 4; ++k) {
      const float* wrow = wvp + (size_t)(ig * 4 + k) * HH;
      float4 w0 = *(const float4*)(wrow);
      float4 w1 = *(const float4*)(wrow + 4);
#pragma unroll
      for (int r = 0; r < 8; ++r) {
        float av = (k == 0) ? a4[r].x : (k == 1) ? a4[r].y
                 : (k == 2) ? a4[r].z : a4[r].w;
        accr[r][0] += av * w0.x; accr[r][1] += av * w0.y;
        accr[r][2] += av * w0.z; accr[r][3] += av * w0.w;
        accr[r][4] += av * w1.x; accr[r][5] += av * w1.y;
        accr[r][6] += av * w1.z; accr[r][7] += av * w1.w;
      }
    }
  }
  // epilogue: summary[b,h] = sum_r w_r * relu(v + bv)
  float w8[8];
#pragma unroll
  for (int r = 0; r < 8; ++r) w8[r] = s_w[ty * 8 + r];
  float4 b0 = *(const float4*)(bvv + tx * 8);
  float4 b1 = *(const float4*)(bvv + tx * 8 + 4);
  float bc[8] = {b0.x, b0.y, b0.z, b0.w, b1.x, b1.y, b1.z, b1.w};
  float ob[8];
#pragma unroll
  for (int c = 0; c < 8; ++c) {
    float s = 0.f;
#pragma unroll
    for (int r = 0; r < 8; ++r) s += w8[r] * fmaxf(accr[r][c] + bc[c], 0.f);
    ob[c] = s;
  }
  float* op = out + (size_t)(bb * 8 + ty) * HH + tx * 8;
  *(float4*)(op)     = make_float4(ob[0], ob[1], ob[2], ob[3]);
  *(float4*)(op + 4) = make_float4(ob[4], ob[5], ob[6], ob[7]);
}

// ---------------------------------------------------------------------------
extern "C" void kernel_launch(void* const* d_in, const int* in_sizes, int n_in,
                              void* d_out, int out_size, void* d_ws, size_t ws_size,
                              hipStream_t stream) {
  const float* cs  = (const float*)d_in[0];
  const float* X   = (const float*)d_in[1];
  const int*   vm  = (const int*)d_in[2];
  const float* Wq  = (const float*)d_in[3];
  const float* bq  = (const float*)d_in[4];
  const float* Wk  = (const float*)d_in[5];
  const float* bk  = (const float*)d_in[6];
  const float* Wv  = (const float*)d_in[7];
  const float* bvp = (const float*)d_in[8];
  float* out = (float*)d_out;
  float* ws  = (float*)d_ws;

  float* M2T  = ws + WS_M2T;
  float* dvec = ws + WS_D;
  float* evec = ws + WS_E;
  float* fsc  = ws + WS_F;
  int*   wsI  = (int*)(ws + WS_IDX);
  float* wsW  = ws + WS_W;

  hipLaunchKernelGGL(prep_kernel, dim3(HH), dim3(HH), 0, stream,
                     Wq, bq, Wk, bk, M2T, dvec, evec, fsc);
  hipLaunchKernelGGL(attn_kernel, dim3(BB), dim3(HH), 0, stream,
                     cs, X, vm, M2T, dvec, evec, fsc, out, wsI, wsW);
  hipLaunchKernelGGL(summ_kernel, dim3(BB / 8), dim3(HH), 0, stream,
                     X, Wv, bvp, wsI, wsW, out);
}